// Round 16
// baseline (129.886 us; speedup 1.0000x reference)
//
#include <hip/hip_runtime.h>

typedef _Float16 f16x8 __attribute__((ext_vector_type(8)));
typedef _Float16 f16x4 __attribute__((ext_vector_type(4)));
typedef float f32x4 __attribute__((ext_vector_type(4)));

#define MFMA32(A, B, C) __builtin_amdgcn_mfma_f32_16x16x32_f16(A, B, C, 0, 0, 0)
#define MFMA16(A, B, C) __builtin_amdgcn_mfma_f32_16x16x16f16(A, B, C, 0, 0, 0)

struct P16 { f16x8 hi, lo; };
struct P8  { f16x4 hi, lo; };

__device__ __forceinline__ P16 split16(float4 a, float4 b) {
  float v[8] = {a.x, a.y, a.z, a.w, b.x, b.y, b.z, b.w};
  P16 p;
#pragma unroll
  for (int e = 0; e < 8; ++e) {
    const _Float16 h = (_Float16)v[e];
    p.hi[e] = h; p.lo[e] = (_Float16)(v[e] - (float)h);
  }
  return p;
}
__device__ __forceinline__ P8 split4(float a0, float a1, float a2, float a3) {
  float v[4] = {a0, a1, a2, a3};
  P8 p;
#pragma unroll
  for (int e = 0; e < 4; ++e) {
    const _Float16 h = (_Float16)v[e];
    p.hi[e] = h; p.lo[e] = (_Float16)(v[e] - (float)h);
  }
  return p;
}
__device__ __forceinline__ float sigm(float a) {
  return __builtin_amdgcn_rcpf(1.0f + __expf(-a));
}

// W [512][28] f32 -> f16 hi/lo fragment planes: wf[{0,1}*32 + T][lane] = uint4
__global__ void prep_wfrag(const float* __restrict__ W, uint4* __restrict__ wf) {
  const int id = blockIdx.x * 256 + threadIdx.x;
  if (id >= 2048) return;
  const int T = id >> 6, l = id & 63, g = (l >> 4) & 3, li = l & 15;
  const int col = 16 * T + li;
  unsigned hi[8], lo[8];
#pragma unroll
  for (int e = 0; e < 8; ++e) {
    const int k = (e < 4) ? (4 * g + e) : (16 + 4 * g + (e - 4));
    const float v = (k < 28) ? W[col * 28 + k] : 0.0f;
    const _Float16 h = (_Float16)v;
    const _Float16 lw = (_Float16)(v - (float)h);
    hi[e] = __builtin_bit_cast(unsigned short, h);
    lo[e] = __builtin_bit_cast(unsigned short, lw);
  }
  uint4 uh, ul;
  uh.x = hi[0] | (hi[1] << 16); uh.y = hi[2] | (hi[3] << 16);
  uh.z = hi[4] | (hi[5] << 16); uh.w = hi[6] | (hi[7] << 16);
  ul.x = lo[0] | (lo[1] << 16); ul.y = lo[2] | (lo[3] << 16);
  ul.z = lo[4] | (lo[5] << 16); ul.w = lo[6] | (lo[7] << 16);
  wf[T * 64 + l] = uh;
  wf[(32 + T) * 64 + l] = ul;
}

// x A-fragment loader (shared by kernels A and B): rows base+li / base+16+li,
// cols 4gl.. / 16+4gl.. from a [28][28] f32 row-major matrix, zero-padded.
__device__ __forceinline__ void load_frags28(const float* __restrict__ m,
                                             int gl, int li, P16& F0, P16& F1) {
  const float4 z4 = {0, 0, 0, 0};
  const float4 a0 = *reinterpret_cast<const float4*>(m + li * 28 + 4 * gl);
  const float4 b0 = (gl < 3) ? *reinterpret_cast<const float4*>(m + li * 28 + 16 + 4 * gl) : z4;
  const int r1 = (li < 12) ? 16 + li : 0;
  float4 a1 = *reinterpret_cast<const float4*>(m + r1 * 28 + 4 * gl);
  float4 b1 = (gl < 3) ? *reinterpret_cast<const float4*>(m + r1 * 28 + 16 + 4 * gl) : z4;
  if (li >= 12) { a1 = z4; b1 = z4; }
  F0 = split16(a0, b0); F1 = split16(a1, b1);
}

// KERNEL A: one block = one sample, 4 waves; wave q does H+G for tiles 8q..8q+7;
// park partials; ONE barrier; waves 1-3 exit; wave 0 reduces, solves, writes
// Y^T (f32 [28][28]) into Xout[n] (scratch; kernel C restores X=x afterwards).
__global__ __launch_bounds__(256, 4) void elm_phase_a(
    const float* __restrict__ x, const uint4* __restrict__ wf,
    const float* __restrict__ bias, float* __restrict__ Yt_out)
{
  __shared__ __align__(16) float sm[4096];   // 16 KB: 4 x 1024-word wave regions
  const int tid = threadIdx.x, n = blockIdx.x;
  const int q = tid >> 6, l = tid & 63, gl = l >> 4, li = l & 15;
  const int wb = q * 1024;
  const float* xi = x + (size_t)n * 784;

  P16 X0, X1;
  load_frags28(xi, gl, li, X0, X1);

  // H (8 tiles) + intra-wave transpose + G partial accumulate
  f32x4 d00 = {0, 0, 0, 0}, d01 = {0, 0, 0, 0}, d11 = {0, 0, 0, 0};
  const int sx = li & 7;
#pragma unroll 2
  for (int t = 0; t < 8; ++t) {
    const int T = 8 * q + t;
    const f16x8 Whi = __builtin_bit_cast(f16x8, wf[T * 64 + l]);
    const f16x8 Wlo = __builtin_bit_cast(f16x8, wf[(32 + T) * 64 + l]);
    f32x4 a0 = {0, 0, 0, 0}, a1 = {0, 0, 0, 0};
    a0 = MFMA32(X0.hi, Whi, a0); a0 = MFMA32(X0.hi, Wlo, a0); a0 = MFMA32(X0.lo, Whi, a0);
    a1 = MFMA32(X1.hi, Whi, a1); a1 = MFMA32(X1.hi, Wlo, a1); a1 = MFMA32(X1.lo, Whi, a1);
    const float bv = bias[16 * T + li];
    float4 h0, h1;
    h0.x = sigm(a0[0] + bv); h0.y = sigm(a0[1] + bv);
    h0.z = sigm(a0[2] + bv); h0.w = sigm(a0[3] + bv);
    h1.x = (16 + 4 * gl + 0 < 28) ? sigm(a1[0] + bv) : 0.0f;
    h1.y = (16 + 4 * gl + 1 < 28) ? sigm(a1[1] + bv) : 0.0f;
    h1.z = (16 + 4 * gl + 2 < 28) ? sigm(a1[2] + bv) : 0.0f;
    h1.w = (16 + 4 * gl + 3 < 28) ? sigm(a1[3] + bv) : 0.0f;
    const int tb = wb + (t & 1) * 512;          // transpose dbuf
    *reinterpret_cast<float4*>(&sm[tb + li * 32 + ((gl ^ sx) << 2)]) = h0;
    *reinterpret_cast<float4*>(&sm[tb + li * 32 + (((4 + gl) ^ sx) << 2)]) = h1;
    float a0e[4], a1e[4];
#pragma unroll
    for (int e = 0; e < 4; ++e) {
      const int c = 4 * gl + e;
      const int base = tb + c * 32 + (li & 3);
      a0e[e] = sm[base + ((((li >> 2)    ) ^ (c & 7)) << 2)];
      a1e[e] = sm[base + ((((li >> 2) + 4) ^ (c & 7)) << 2)];
    }
    const P8 A0 = split4(a0e[0], a0e[1], a0e[2], a0e[3]);
    const P8 A1 = split4(a1e[0], a1e[1], a1e[2], a1e[3]);
    d00 = MFMA16(A0.hi, A0.hi, d00); d00 = MFMA16(A0.hi, A0.lo, d00); d00 = MFMA16(A0.lo, A0.hi, d00);
    d01 = MFMA16(A0.hi, A1.hi, d01); d01 = MFMA16(A0.hi, A1.lo, d01); d01 = MFMA16(A0.lo, A1.hi, d01);
    d11 = MFMA16(A1.hi, A1.hi, d11); d11 = MFMA16(A1.hi, A1.lo, d11); d11 = MFMA16(A1.lo, A1.hi, d11);
  }

  // waves 1-3 park partials in their own (dead) transpose regions
  if (q != 0) {
    const int pk = wb + l * 12;
    *reinterpret_cast<float4*>(&sm[pk + 0]) = float4{d00[0], d00[1], d00[2], d00[3]};
    *reinterpret_cast<float4*>(&sm[pk + 4]) = float4{d01[0], d01[1], d01[2], d01[3]};
    *reinterpret_cast<float4*>(&sm[pk + 8]) = float4{d11[0], d11[1], d11[2], d11[3]};
  }
  __syncthreads();
  if (q != 0) return;                           // free the SIMD slots

  // wave 0: reduce partner partials
#pragma unroll
  for (int p = 1; p < 4; ++p) {
    const int pk = p * 1024 + l * 12;
    const float4 u = *reinterpret_cast<const float4*>(&sm[pk + 0]);
    const float4 v = *reinterpret_cast<const float4*>(&sm[pk + 4]);
    const float4 t = *reinterpret_cast<const float4*>(&sm[pk + 8]);
    d00[0] += u.x; d00[1] += u.y; d00[2] += u.z; d00[3] += u.w;
    d01[0] += v.x; d01[1] += v.y; d01[2] += v.z; d01[3] += v.w;
    d11[0] += t.x; d11[1] += t.y; d11[2] += t.z; d11[3] += t.w;
  }
  // Gc (+mirror) into own region [0,896)
#pragma unroll
  for (int i = 0; i < 4; ++i) {
    const int ra = 4 * gl + i;
    sm[ra * 32 + li] = d00[i];
    sm[li * 32 + ra] = d00[i];
    sm[ra * 32 + 16 + li] = d01[i];
    sm[(16 + li) * 32 + ra] = d01[i];
    sm[(16 + ra) * 32 + 16 + li] = d11[i];
    sm[(16 + li) * 32 + 16 + ra] = d11[i];
  }
  // solve G Y = x (Gauss-Jordan, intra-wave); write Y^T -> Yt_out[n]
  {
    const int j = l;
    float col[28];
#pragma unroll
    for (int r = 0; r < 28; ++r) {
      float v = 0.f;
      if (j < 28)      v = sm[r * 32 + j];
      else if (j < 56) v = xi[r * 28 + (j - 28)];
      col[r] = v;
    }
#pragma unroll
    for (int k = 0; k < 28; ++k) {
      const float piv = __shfl(col[k], k);
      const float pivinv = 1.0f / piv;
      col[k] *= pivinv;
#pragma unroll
      for (int r2 = 0; r2 < 28; ++r2) {
        if (r2 == k) continue;
        const float m = __shfl(col[r2], k);
        col[r2] -= m * col[k];
      }
    }
    if (j >= 28 && j < 56) {
      const int c = j - 28;
      float* yo = Yt_out + (size_t)n * 784 + c * 28;
#pragma unroll
      for (int r2 = 0; r2 < 28; ++r2) yo[r2] = col[r2];
    }
  }
}

// KERNEL B: one block = one sample, 4 waves, wave q does tiles 8q..8q+7.
// Zero LDS, zero barriers. Yt read from Xout scratch (written by kernel A).
__global__ __launch_bounds__(256, 4) void elm_phase_b(
    const float* __restrict__ x, const float* __restrict__ yt,
    const uint4* __restrict__ wf, const float* __restrict__ bias,
    float* __restrict__ Bout)
{
  const int tid = threadIdx.x, n = blockIdx.x;
  const int q = tid >> 6, l = tid & 63, gl = l >> 4, li = l & 15;
  const float* xi = x + (size_t)n * 784;
  const float* yi = yt + (size_t)n * 784;

  P16 X0, X1, Y0, Y1;
  load_frags28(xi, gl, li, X0, X1);
  load_frags28(yi, gl, li, Y0, Y1);

  float* Bo = Bout + (size_t)n * 14336;
#pragma unroll 2
  for (int t = 0; t < 8; ++t) {
    const int T = 8 * q + t;
    const f16x8 Whi = __builtin_bit_cast(f16x8, wf[T * 64 + l]);
    const f16x8 Wlo = __builtin_bit_cast(f16x8, wf[(32 + T) * 64 + l]);
    f32x4 a0 = {0, 0, 0, 0}, a1 = {0, 0, 0, 0};
    a0 = MFMA32(X0.hi, Whi, a0); a0 = MFMA32(X0.hi, Wlo, a0); a0 = MFMA32(X0.lo, Whi, a0);
    a1 = MFMA32(X1.hi, Whi, a1); a1 = MFMA32(X1.hi, Wlo, a1); a1 = MFMA32(X1.lo, Whi, a1);
    const float bv = bias[16 * T + li];
    f16x8 Bhi, Blo;
#pragma unroll
    for (int i = 0; i < 4; ++i) {
      const float h0 = sigm(a0[i] + bv);
      const _Float16 hh0 = (_Float16)h0;
      Bhi[i] = hh0; Blo[i] = (_Float16)(h0 - (float)hh0);
      const float h1 = (16 + 4 * gl + i < 28) ? sigm(a1[i] + bv) : 0.0f;
      const _Float16 hh1 = (_Float16)h1;
      Bhi[4 + i] = hh1; Blo[4 + i] = (_Float16)(h1 - (float)hh1);
    }
    f32x4 bt0 = {0, 0, 0, 0}, bt1 = {0, 0, 0, 0};
    bt0 = MFMA32(Y0.hi, Bhi, bt0); bt0 = MFMA32(Y0.hi, Blo, bt0); bt0 = MFMA32(Y0.lo, Bhi, bt0);
    bt1 = MFMA32(Y1.hi, Bhi, bt1); bt1 = MFMA32(Y1.hi, Blo, bt1); bt1 = MFMA32(Y1.lo, Bhi, bt1);
    float* Brow = Bo + (16 * T + li) * 28;
    *reinterpret_cast<float4*>(Brow + 4 * gl) = float4{bt0[0], bt0[1], bt0[2], bt0[3]};
    if (gl < 3)
      *reinterpret_cast<float4*>(Brow + 16 + 4 * gl) = float4{bt1[0], bt1[1], bt1[2], bt1[3]};
  }
}

// KERNEL C: X = x (overwrites the Yt scratch), 802816 float4s.
__global__ __launch_bounds__(256) void elm_copy_x(
    const float* __restrict__ x, float* __restrict__ Xout, int total4)
{
  const int i = blockIdx.x * 256 + threadIdx.x;
  if (i < total4)
    reinterpret_cast<float4*>(Xout)[i] = reinterpret_cast<const float4*>(x)[i];
}

extern "C" void kernel_launch(void* const* d_in, const int* in_sizes, int n_in,
                              void* d_out, int out_size, void* d_ws, size_t ws_size,
                              hipStream_t stream) {
  const float* x = (const float*)d_in[0];
  const float* W = (const float*)d_in[1];
  const float* b = (const float*)d_in[2];
  const int N = in_sizes[0] / 784;               // 4096 samples
  float* Xout = (float*)d_out;                   // [N,1,28,28]
  float* Bout = Xout + (size_t)N * 784;          // [N,1,512,28]
  uint4* wf = (uint4*)d_ws;                      // 65536 B
  prep_wfrag<<<8, 256, 0, stream>>>(W, wf);
  elm_phase_a<<<N, 256, 0, stream>>>(x, wf, b, Xout);        // Yt -> Xout scratch
  elm_phase_b<<<N, 256, 0, stream>>>(x, Xout, wf, b, Bout);  // reads Yt, writes B
  const int total4 = N * 196;
  elm_copy_x<<<(total4 + 255) / 256, 256, 0, stream>>>(x, Xout, total4);
}

// Round 17
// 104.833 us; speedup vs baseline: 1.2390x; 1.2390x over previous
//
#include <hip/hip_runtime.h>

typedef _Float16 f16x8 __attribute__((ext_vector_type(8)));
typedef float f32x4 __attribute__((ext_vector_type(4)));

#define MFMA32(A, B, C) __builtin_amdgcn_mfma_f32_16x16x32_f16(A, B, C, 0, 0, 0)

struct P16 { f16x8 hi, lo; };

__device__ __forceinline__ P16 split16(float4 a, float4 b) {
  float v[8] = {a.x, a.y, a.z, a.w, b.x, b.y, b.z, b.w};
  P16 p;
#pragma unroll
  for (int e = 0; e < 8; ++e) {
    const _Float16 h = (_Float16)v[e];
    p.hi[e] = h; p.lo[e] = (_Float16)(v[e] - (float)h);
  }
  return p;
}
__device__ __forceinline__ P16 split8a(const float* v) {
  P16 p;
#pragma unroll
  for (int e = 0; e < 8; ++e) {
    const _Float16 h = (_Float16)v[e];
    p.hi[e] = h; p.lo[e] = (_Float16)(v[e] - (float)h);
  }
  return p;
}
__device__ __forceinline__ float sigm(float a) {
  return __builtin_amdgcn_rcpf(1.0f + __expf(-a));
}

// prep: W [512][28] f32 -> f16 hi/lo fragment planes wf[{0,1}*32+T][lane];
// element e: k = 4g+e (e<4) | 16+4g+(e-4), g=lane>>4; W-col = 16T + (lane&15).
// ALSO bias fragments bf[(s*64+l)*2 + {0,1}]: h = 32s + pattern(g,e).
__global__ void prep_wfrag(const float* __restrict__ W, const float* __restrict__ bias,
                           uint4* __restrict__ wf, f32x4* __restrict__ bf) {
  const int id = blockIdx.x * 256 + threadIdx.x;
  if (id < 2048) {
    const int T = id >> 6, l = id & 63, g = (l >> 4) & 3, li = l & 15;
    const int col = 16 * T + li;
    unsigned hi[8], lo[8];
#pragma unroll
    for (int e = 0; e < 8; ++e) {
      const int k = (e < 4) ? (4 * g + e) : (16 + 4 * g + (e - 4));
      const float v = (k < 28) ? W[col * 28 + k] : 0.0f;
      const _Float16 h = (_Float16)v;
      const _Float16 lw = (_Float16)(v - (float)h);
      hi[e] = __builtin_bit_cast(unsigned short, h);
      lo[e] = __builtin_bit_cast(unsigned short, lw);
    }
    uint4 uh, ul;
    uh.x = hi[0] | (hi[1] << 16); uh.y = hi[2] | (hi[3] << 16);
    uh.z = hi[4] | (hi[5] << 16); uh.w = hi[6] | (hi[7] << 16);
    ul.x = lo[0] | (lo[1] << 16); ul.y = lo[2] | (lo[3] << 16);
    ul.z = lo[4] | (lo[5] << 16); ul.w = lo[6] | (lo[7] << 16);
    wf[T * 64 + l] = uh;
    wf[(32 + T) * 64 + l] = ul;
  }
  if (id < 1024) {
    const int s = id >> 6, l = id & 63, g = (l >> 4) & 3;
    f32x4 b0, b1;
#pragma unroll
    for (int e = 0; e < 4; ++e) {
      b0[e] = bias[32 * s + 4 * g + e];
      b1[e] = bias[32 * s + 16 + 4 * g + e];
    }
    bf[id * 2 + 0] = b0;
    bf[id * 2 + 1] = b1;
  }
}

// ONE WAVE = ONE SAMPLE (R15 base, 111us) with the G-phase LDS transpose
// ELIMINATED: Ht computed directly via swapped-operand MFMA32(W, X) -> output
// fragment (lane = x-row r, regs = h 4gl+i) IS the G-MFMA operand fragment
// (lane = non-k idx, elems = k pattern) -> G += MFMA32(F, F), F self-both-operands
// (G symmetric). Garbage in G rows/cols >= 28 (padded r lanes) is never read.
// LDS use: only per-wave Gc[28][32] / Yt[32][32] (1024 words). ZERO barriers.
__global__ __launch_bounds__(256, 4) void elm_kernel(
    const float* __restrict__ x, const uint4* __restrict__ wf,
    const f32x4* __restrict__ bf, const float* __restrict__ bias,
    float* __restrict__ Xout, float* __restrict__ Bout)
{
  __shared__ __align__(16) float sm[4096];   // 4 x 1024-word wave regions
  const int tid = threadIdx.x;
  const int w = tid >> 6, l = tid & 63, gl = l >> 4, li = l & 15;
  const int n = blockIdx.x * 4 + w;
  const int wb = w * 1024;
  const float* xi = x + (size_t)n * 784;

  // ---- 1. X = x (coalesced per-wave copy) ----
  {
    const float4* x4 = reinterpret_cast<const float4*>(xi);
    float4* X4 = reinterpret_cast<float4*>(Xout + (size_t)n * 784);
#pragma unroll
    for (int k = 0; k < 4; ++k) {
      const int idx = l + 64 * k;
      if (idx < 196) X4[idx] = x4[idx];
    }
  }

  // ---- 2. x fragments (lane = x-row li / 16+li, elems = x-cols) ----
  const float4 z4 = {0, 0, 0, 0};
  const float4 xa0 = *reinterpret_cast<const float4*>(xi + li * 28 + 4 * gl);
  const float4 xb0 = (gl < 3) ? *reinterpret_cast<const float4*>(xi + li * 28 + 16 + 4 * gl) : z4;
  const int r1 = (li < 12) ? 16 + li : 0;
  float4 xa1 = *reinterpret_cast<const float4*>(xi + r1 * 28 + 4 * gl);
  float4 xb1 = (gl < 3) ? *reinterpret_cast<const float4*>(xi + r1 * 28 + 16 + 4 * gl) : z4;
  if (li >= 12) { xa1 = z4; xb1 = z4; }
  const P16 X0 = split16(xa0, xb0);
  const P16 X1 = split16(xa1, xb1);

  // ---- 3. G phase: 16 chunks of 32 h; Ht via MFMA32(W, X); NO LDS ----
  f32x4 d00 = {0, 0, 0, 0}, d01 = {0, 0, 0, 0}, d11 = {0, 0, 0, 0};
#pragma unroll 2
  for (int s = 0; s < 16; ++s) {
    const int t0 = 2 * s, t1 = 2 * s + 1;
    const f16x8 W0h = __builtin_bit_cast(f16x8, wf[t0 * 64 + l]);
    const f16x8 W0l = __builtin_bit_cast(f16x8, wf[(32 + t0) * 64 + l]);
    const f16x8 W1h = __builtin_bit_cast(f16x8, wf[t1 * 64 + l]);
    const f16x8 W1l = __builtin_bit_cast(f16x8, wf[(32 + t1) * 64 + l]);
    const f32x4 ba = bf[(s * 64 + l) * 2 + 0];
    const f32x4 bb = bf[(s * 64 + l) * 2 + 1];
    f32x4 P0 = {0, 0, 0, 0}, Q0 = {0, 0, 0, 0}, P1 = {0, 0, 0, 0}, Q1 = {0, 0, 0, 0};
    P0 = MFMA32(W0h, X0.hi, P0); P0 = MFMA32(W0h, X0.lo, P0); P0 = MFMA32(W0l, X0.hi, P0);
    Q0 = MFMA32(W1h, X0.hi, Q0); Q0 = MFMA32(W1h, X0.lo, Q0); Q0 = MFMA32(W1l, X0.hi, Q0);
    P1 = MFMA32(W0h, X1.hi, P1); P1 = MFMA32(W0h, X1.lo, P1); P1 = MFMA32(W0l, X1.hi, P1);
    Q1 = MFMA32(W1h, X1.hi, Q1); Q1 = MFMA32(W1h, X1.lo, Q1); Q1 = MFMA32(W1l, X1.hi, Q1);
    float f0[8], f1[8];
#pragma unroll
    for (int i = 0; i < 4; ++i) {
      f0[i]     = sigm(P0[i] + ba[i]);
      f0[4 + i] = sigm(Q0[i] + bb[i]);
      f1[i]     = sigm(P1[i] + ba[i]);
      f1[4 + i] = sigm(Q1[i] + bb[i]);
    }
    const P16 F0 = split8a(f0);
    const P16 F1 = split8a(f1);
    d00 = MFMA32(F0.hi, F0.hi, d00); d00 = MFMA32(F0.hi, F0.lo, d00); d00 = MFMA32(F0.lo, F0.hi, d00);
    d01 = MFMA32(F0.hi, F1.hi, d01); d01 = MFMA32(F0.hi, F1.lo, d01); d01 = MFMA32(F0.lo, F1.hi, d01);
    d11 = MFMA32(F1.hi, F1.hi, d11); d11 = MFMA32(F1.hi, F1.lo, d11); d11 = MFMA32(F1.lo, F1.hi, d11);
  }

  // ---- 4. G fragments -> per-wave LDS Gc[r*32+c] (d01 mirrored = d10) ----
#pragma unroll
  for (int i = 0; i < 4; ++i) {
    const int ra = 4 * gl + i;
    sm[wb + ra * 32 + li] = d00[i];
    sm[wb + ra * 32 + 16 + li] = d01[i];
    sm[wb + (16 + li) * 32 + ra] = d01[i];
    sm[wb + (16 + ra) * 32 + 16 + li] = d11[i];
  }

  // ---- 5. solve G Y = x : per-wave Gauss-Jordan; RHS from global x ----
  {
    const int j = l;
    float col[28];
#pragma unroll
    for (int r = 0; r < 28; ++r) {
      float v = 0.f;
      if (j < 28)      v = sm[wb + r * 32 + j];
      else if (j < 56) v = xi[r * 28 + (j - 28)];
      col[r] = v;
    }
#pragma unroll
    for (int k = 0; k < 28; ++k) {
      const float piv = __shfl(col[k], k);
      const float pivinv = 1.0f / piv;
      col[k] *= pivinv;
#pragma unroll
      for (int r2 = 0; r2 < 28; ++r2) {
        if (r2 == k) continue;
        const float m = __shfl(col[r2], k);
        col[r2] -= m * col[k];
      }
    }
    if (j >= 28 && j < 56) {          // Y^T: sm[c*32 + r]; zero col-pads
      const int c = j - 28;
#pragma unroll
      for (int r2 = 0; r2 < 28; ++r2) sm[wb + c * 32 + r2] = col[r2];
      *reinterpret_cast<float4*>(&sm[wb + c * 32 + 28]) = z4;
    }
    if (j >= 56) {                    // zero pad rows 28..31 (2 lanes/row)
      const int rr = 28 + ((j - 56) >> 1), half = (j - 56) & 1;
#pragma unroll
      for (int t = 0; t < 4; ++t)
        *reinterpret_cast<float4*>(&sm[wb + rr * 32 + half * 16 + 4 * t]) = z4;
    }
  }

  // ---- 6. Y A-fragments from per-wave Yt ----
  const P16 Y0 = split16(*reinterpret_cast<const float4*>(&sm[wb + li * 32 + 4 * gl]),
                         *reinterpret_cast<const float4*>(&sm[wb + li * 32 + 16 + 4 * gl]));
  const P16 Y1 = split16(*reinterpret_cast<const float4*>(&sm[wb + (16 + li) * 32 + 4 * gl]),
                         *reinterpret_cast<const float4*>(&sm[wb + (16 + li) * 32 + 16 + 4 * gl]));

  // ---- 7. B = H~^T Y : recompute H (old orientation); direct stores ----
  float* Bo = Bout + (size_t)n * 14336;
#pragma unroll 2
  for (int T = 0; T < 32; ++T) {
    const f16x8 Whi = __builtin_bit_cast(f16x8, wf[T * 64 + l]);
    const f16x8 Wlo = __builtin_bit_cast(f16x8, wf[(32 + T) * 64 + l]);
    f32x4 a0 = {0, 0, 0, 0}, a1 = {0, 0, 0, 0};
    a0 = MFMA32(X0.hi, Whi, a0); a0 = MFMA32(X0.hi, Wlo, a0); a0 = MFMA32(X0.lo, Whi, a0);
    a1 = MFMA32(X1.hi, Whi, a1); a1 = MFMA32(X1.hi, Wlo, a1); a1 = MFMA32(X1.lo, Whi, a1);
    const float bv = bias[16 * T + li];
    f16x8 Bhi, Blo;
#pragma unroll
    for (int i = 0; i < 4; ++i) {
      const float h0 = sigm(a0[i] + bv);
      const _Float16 hh0 = (_Float16)h0;
      Bhi[i] = hh0; Blo[i] = (_Float16)(h0 - (float)hh0);
      const float h1 = (16 + 4 * gl + i < 28) ? sigm(a1[i] + bv) : 0.0f;
      const _Float16 hh1 = (_Float16)h1;
      Bhi[4 + i] = hh1; Blo[4 + i] = (_Float16)(h1 - (float)hh1);
    }
    f32x4 bt0 = {0, 0, 0, 0}, bt1 = {0, 0, 0, 0};
    bt0 = MFMA32(Y0.hi, Bhi, bt0); bt0 = MFMA32(Y0.hi, Blo, bt0); bt0 = MFMA32(Y0.lo, Bhi, bt0);
    bt1 = MFMA32(Y1.hi, Bhi, bt1); bt1 = MFMA32(Y1.hi, Blo, bt1); bt1 = MFMA32(Y1.lo, Bhi, bt1);
    float* Brow = Bo + (16 * T + li) * 28;
    *reinterpret_cast<float4*>(Brow + 4 * gl) = float4{bt0[0], bt0[1], bt0[2], bt0[3]};
    if (gl < 3)
      *reinterpret_cast<float4*>(Brow + 16 + 4 * gl) = float4{bt1[0], bt1[1], bt1[2], bt1[3]};
  }
}

extern "C" void kernel_launch(void* const* d_in, const int* in_sizes, int n_in,
                              void* d_out, int out_size, void* d_ws, size_t ws_size,
                              hipStream_t stream) {
  const float* x = (const float*)d_in[0];
  const float* W = (const float*)d_in[1];
  const float* b = (const float*)d_in[2];
  const int N = in_sizes[0] / 784;               // 4096 samples
  float* Xout = (float*)d_out;                   // [N,1,28,28]
  float* Bout = Xout + (size_t)N * 784;          // [N,1,512,28]
  uint4* wf = (uint4*)d_ws;                      // 65536 B
  f32x4* bfr = (f32x4*)((char*)d_ws + 65536);    // 32768 B
  prep_wfrag<<<8, 256, 0, stream>>>(W, b, wf, bfr);
  elm_kernel<<<N / 4, 256, 0, stream>>>(x, wf, bfr, b, Xout, Bout);
}